// Round 1
// baseline (563.824 us; speedup 1.0000x reference)
//
#include <hip/hip_runtime.h>
#include <cstdint>
#include <cmath>

// Problem dims
#define B_   128
#define N_   196
#define D_   768
#define H_   3072
#define R_   384
#define TOK  (B_*N_)      // 25088

typedef int i32x4 __attribute__((ext_vector_type(4)));

// async global->LDS, 16B per lane; LDS dest = wave-uniform base + lane*16
#define GLDS16(g, l) __builtin_amdgcn_global_load_lds( \
    (const __attribute__((address_space(1))) void*)(g), \
    (__attribute__((address_space(3))) void*)(l), 16, 0, 0)

// s_waitcnt imm (gfx9): vmcnt[3:0], expcnt[6:4]=7, lgkmcnt[11:8]=15, vmcnt hi[15:14]=0
#define WAITV4() __builtin_amdgcn_s_waitcnt(0xF74)   // vmcnt(4)
#define WAITV0() __builtin_amdgcn_s_waitcnt(0xF70)   // vmcnt(0)
#define BARRIER() do { __asm__ volatile("" ::: "memory"); \
                       __builtin_amdgcn_s_barrier(); \
                       __asm__ volatile("" ::: "memory"); } while (0)

// ---------------- workspace layout (bytes) ----------------
#define OFF_AMAX   0L
#define OFF_LUT    512L                  // 256-entry int8 GELU LUT
#define OFF_QVEC   1024L                 // 6 x 768 fp32 precomputed epilogue vectors
#define OFF_WQA    (32L*1024)            // attn weight int8 padded [256][256]
#define OFF_W1VT   (128L*1024)           // [384][768]
#define OFF_W1U    (512L*1024)           // [3072][384]
#define OFF_W2VT   (2L*1024*1024)        // [384][3072]
#define OFF_W2U    (3328L*1024)          // [768][384]
#define OFF_X1Q    (4L*1024*1024)        // int8 [25088][768]
#define OFF_A4     (24L*1024*1024)       // int8 [25088][384]
#define OFF_A7     (34L*1024*1024)       // int8 [25088][384]
#define OFF_A0T    (44L*1024*1024)       // int8 [128][768][256] (dead after attn)
#define OFF_A2     (68L*1024*1024)       // int8 [25088][768]    (dead after fc1_vt)
#define OFF_A6     (44L*1024*1024)       // int8 [25088][3072]   (overlays A0T+A2)

__device__ __forceinline__ float rclipf(float v) {
  // clip(round_half_even(v), -128, 127) ; matches jnp.clip(jnp.round(x),-n,n-1)
  return fminf(fmaxf(rintf(v), -128.f), 127.f);
}

// ---------------- absmax over 9 weight tensors ----------------
__global__ void absmax_k(const float* p0, const float* p1, const float* p2,
                         const float* p3, const float* p4, const float* p5,
                         const float* p6, const float* p7, const float* p8,
                         float* amax) {
  int tsel = blockIdx.y;
  const float* src; int n;
  switch (tsel) {
    case 0: src = p0; n = 768;     break;  // norm1_a
    case 1: src = p1; n = N_*N_;   break;  // attn_w
    case 2: src = p2; n = 768;     break;  // gamma1
    case 3: src = p3; n = 768;     break;  // norm2_a
    case 4: src = p4; n = R_*D_;   break;  // fc1_vt_w
    case 5: src = p5; n = H_*R_;   break;  // fc1_u_w
    case 6: src = p6; n = R_*H_;   break;  // fc2_vt_w
    case 7: src = p7; n = D_*R_;   break;  // fc2_u_w
    default: src = p8; n = 768;    break;  // gamma2
  }
  float m = 0.f;
  for (int i = blockIdx.x*blockDim.x + threadIdx.x; i < n; i += gridDim.x*blockDim.x)
    m = fmaxf(m, fabsf(src[i]));
  #pragma unroll
  for (int off = 32; off > 0; off >>= 1)
    m = fmaxf(m, __shfl_down(m, off));
  if ((threadIdx.x & 63) == 0)
    atomicMax((int*)(amax + tsel), __float_as_int(m));  // non-negative floats: int order == float order
}

// ---------------- precompute epilogue vectors + GELU LUT (1 block, 768 thr) ----------------
__global__ void prep_vec_k(const float* n1a, const float* n1b, const float* g1,
                           const float* n2a, const float* n2b, const float* g2,
                           const float* amax, const float* actS, float* dst,
                           int8_t* lut) {
  int i = threadIdx.x;  // 768
  float s0 = actS[0], s1 = actS[1], s2 = actS[2], s3 = actS[3];
  float s8 = actS[8], s9 = actS[9];
  float sw;
  sw = amax[0]/127.f + 1e-8f; float qn1a = sw * rclipf(n1a[i]/sw);
  dst[i]        = qn1a / s0;
  dst[768+i]    = n1b[i] / s0;
  sw = amax[2]/127.f + 1e-8f; float qg1 = sw * rclipf(g1[i]/sw);
  dst[1536+i]   = (s1 * qg1) / s8;
  sw = amax[3]/127.f + 1e-8f; float qn2a = sw * rclipf(n2a[i]/sw);
  dst[2304+i]   = (s8 * qn2a) / s2;
  dst[3072+i]   = n2b[i] / s2;
  sw = amax[8]/127.f + 1e-8f; float qg2 = sw * rclipf(g2[i]/sw);
  dst[3840+i]   = (s3 * qg2) / s9;
  if (i < 256) {
    float s5 = actS[5], s6 = actS[6];
    float v5 = s5 * (float)(i - 128);
    float g  = 0.5f * v5 * (1.f + erff(v5 * 0.70710678118654752f));
    lut[i] = (int8_t)(int)rclipf(g / s6);
  }
}

// ---------------- quantize all 5 matmul weights (blockIdx.y selects tensor) ----------------
__global__ void quant_all_k(const float* w1vt, const float* w1u, const float* w2vt,
                            const float* w2u, const float* attw, const float* amax,
                            int8_t* W1VT, int8_t* W1U, int8_t* W2VT, int8_t* W2U,
                            int8_t* WQA) {
  int sel = blockIdx.y;
  const float* src; int8_t* dst; int n; float am;
  switch (sel) {
    case 0: src = w1vt; dst = W1VT; n = R_*D_;  am = amax[4]; break;
    case 1: src = w1u;  dst = W1U;  n = H_*R_;  am = amax[5]; break;
    case 2: src = w2vt; dst = W2VT; n = R_*H_;  am = amax[6]; break;
    case 3: src = w2u;  dst = W2U;  n = D_*R_;  am = amax[7]; break;
    default: src = attw; dst = WQA; n = 65536;  am = amax[1]; break;
  }
  float s = am / 127.f + 1e-8f;
  if (sel < 4) {
    for (int i = blockIdx.x*blockDim.x + threadIdx.x; i < n; i += gridDim.x*blockDim.x)
      dst[i] = (int8_t)(int)rclipf(src[i] / s);
  } else {
    for (int i = blockIdx.x*blockDim.x + threadIdx.x; i < n; i += gridDim.x*blockDim.x) {
      int m = i >> 8, nn = i & 255;
      int8_t q = 0;
      if (m < N_ && nn < N_) q = (int8_t)(int)rclipf(attw[m*N_ + nn] / s);
      dst[i] = q;
    }
  }
}

// ---------------- stage A: norm1 affine + act-quant, transposed to A0T[b][d][n256] ----------------
__global__ void stageA_k(const float* __restrict__ x, const float* __restrict__ n1as,
                         const float* __restrict__ n1bs, int8_t* __restrict__ A0T) {
  __shared__ int8_t ldsT[64*68];
  const int dt = blockIdx.x;   // 0..11 (d tile of 64)
  const int nt = blockIdx.y;   // 0..3  (n tile of 64, n padded to 256)
  const int b  = blockIdx.z;
  const int d0 = dt*64, n0 = nt*64;
  const int tid = threadIdx.x;
  const int dc = tid & 63, nr4 = tid >> 6;
  const float qa = n1as[d0 + dc];
  const float bb = n1bs[d0 + dc];
  #pragma unroll 4
  for (int it = 0; it < 16; ++it) {
    int nl = nr4 + it*4;
    int n = n0 + nl;
    int8_t q = 0;
    if (n < N_) {
      float v = fmaf(x[((long)b*N_ + n)*D_ + d0 + dc], qa, bb);
      q = (int8_t)(int)rclipf(v);
    }
    ldsT[dc*68 + nl] = q;
  }
  __syncthreads();
  const int k = tid & 15, dr = tid >> 4;
  #pragma unroll
  for (int it = 0; it < 4; ++it) {
    int d = dr + it*16;
    uint32_t v = *(const uint32_t*)(&ldsT[d*68 + k*4]);
    *(uint32_t*)(&A0T[(long)b*(D_*256) + (long)(d0+d)*256 + n0 + k*4]) = v;
  }
}

// ---------------- generic i8 GEMM (old LDS-staged path; still used for fc1_VT / fc2_VT) ----
struct GemmParams {
  const int8_t* A;
  const int8_t* W;
  int K, MT, NT;
  long batchStrideA;
  const float* actS;
  const float* amax;
  int amaxIdx, sInIdx, sOutIdx, sOut2Idx;
  const float* bias;
  int8_t* out8;
  int ldOut;
  const float* xorg;
  const float* g1s;
  const float* a2s8;
  const float* b2s;
  int8_t* X1q;
  int8_t* A2;
  const float* g2s9;
  const int8_t* X1qIn;
  float* outF;
  const int8_t* lutG;
};

template<int EPI>
__launch_bounds__(256, 4)
__global__ void gemm_i8(GemmParams p) {
  __shared__ __align__(16) int8_t lsA[2][128][64];
  __shared__ __align__(16) int8_t lsB[2][128][64];
  __shared__ int8_t lut[256];
  const int K  = p.K;
  const int bx = blockIdx.x;
  const int mt = bx % p.MT;
  const int nt = bx / p.MT;
  const int t    = threadIdx.x;
  const int wid  = t >> 6;
  const int lane = t & 63;
  const int wm = wid & 1, wn = wid >> 1;
  const int quad = lane >> 4, l15 = lane & 15;

  if constexpr (EPI == 2) lut[t] = p.lutG[t];

  const int8_t* Abase = p.A + (long)blockIdx.y * p.batchStrideA + (long)mt*128*K;
  const int8_t* Wbase = p.W + (long)nt*128*K;

  const int8_t* Ab = Abase + (long)(t >> 2)*K + (t & 3)*16;
  const int8_t* Bb = Wbase + (long)(t >> 2)*K + (t & 3)*16;
  const long half = 64L * K;

  auto issue = [&](int kt) {
    const int buf = kt & 1;
    const long k = (long)kt << 6;
    GLDS16(Ab + k,        &lsA[buf][0][0]  + t*16);
    GLDS16(Ab + half + k, &lsA[buf][64][0] + t*16);
    GLDS16(Bb + k,        &lsB[buf][0][0]  + t*16);
    GLDS16(Bb + half + k, &lsB[buf][64][0] + t*16);
  };

  const i32x4 zero = {0, 0, 0, 0};
  i32x4 acc[4][4];
  #pragma unroll
  for (int i = 0; i < 4; ++i)
    #pragma unroll
    for (int j = 0; j < 4; ++j) acc[i][j] = zero;

  const int KT = K >> 6;
  issue(0);
  for (int kt = 0; kt < KT; ++kt) {
    const int cur = kt & 1;
    if (kt + 1 < KT) { issue(kt + 1); WAITV4(); }
    else             { WAITV0(); }
    BARRIER();
    i32x4 af[4], bf[4];
    #pragma unroll
    for (int i = 0; i < 4; ++i)
      af[i] = *(const i32x4*)(&lsA[cur][wm*64 + i*16 + l15][quad*16]);
    #pragma unroll
    for (int j = 0; j < 4; ++j)
      bf[j] = *(const i32x4*)(&lsB[cur][wn*64 + j*16 + l15][quad*16]);
    #pragma unroll
    for (int i = 0; i < 4; ++i)
      #pragma unroll
      for (int j = 0; j < 4; ++j)
        acc[i][j] = __builtin_amdgcn_mfma_i32_16x16x64_i8(af[i], bf[j], acc[i][j], 0, 0, 0);
    BARRIER();
  }

  const float sW  = p.amax[p.amaxIdx] / 127.f + 1e-8f;
  const float sAB = p.actS[p.sInIdx] * sW;
  const int i0 = mt*128 + wm*64;
  const int j0 = nt*128 + wn*64;

  #pragma unroll
  for (int ii = 0; ii < 4; ++ii) {
    const int i = i0 + ii*16 + quad*4;
    if constexpr (EPI == 1) {
      const float sO = p.actS[p.sOutIdx];
      const float c1 = sAB / sO;
      const float4 b4 = *(const float4*)(p.bias + i);
      float c2[4];
      #pragma unroll
      for (int r = 0; r < 4; ++r) c2[r] = ((const float*)&b4)[r] / sO;
      #pragma unroll
      for (int jj = 0; jj < 4; ++jj) {
        const int j = j0 + jj*16 + l15;
        uint32_t pk = 0;
        #pragma unroll
        for (int r = 0; r < 4; ++r) {
          float q = rclipf(fmaf((float)acc[ii][jj][r], c1, c2[r]));
          pk |= ((uint32_t)(uint8_t)(int8_t)(int)q) << (8*r);
        }
        *(uint32_t*)(p.out8 + (long)j*p.ldOut + i) = pk;
      }
    } else if constexpr (EPI == 2) {
      const float s5v = p.actS[p.sOutIdx];
      const float c1 = sAB / s5v;
      const float4 b4 = *(const float4*)(p.bias + i);
      float c2[4];
      #pragma unroll
      for (int r = 0; r < 4; ++r) c2[r] = ((const float*)&b4)[r] / s5v;
      #pragma unroll
      for (int jj = 0; jj < 4; ++jj) {
        const int j = j0 + jj*16 + l15;
        uint32_t pk = 0;
        #pragma unroll
        for (int r = 0; r < 4; ++r) {
          int q5 = (int)rclipf(fmaf((float)acc[ii][jj][r], c1, c2[r])) + 128;
          pk |= ((uint32_t)(uint8_t)lut[q5]) << (8*r);
        }
        *(uint32_t*)(p.out8 + (long)j*p.ldOut + i) = pk;
      }
    }
  }
}

// ---------------- weight-resident barrier-free i8 GEMM (K<=384) ----------------
// Resident operand lives in VGPRs for the whole block (KT*4 i32x4 frags/wave).
// Streamed operand goes global->reg with a one-kk-ahead double buffer; the 4
// waves of a block share the SAME streamed tile (L1-merged) and own disjoint
// resident rows (RESB: resident = B/cols = attn m; else resident = A/rows =
// weight features). No LDS staging, no barriers in the K-loop.
// EPI: 0=attn(+gamma1+res+norm2+act3)  2=quant+GELU LUT  3=final fp32
struct WresParams {
  const int8_t* Wres;    // resident operand, row stride = K
  const int8_t* Astr;    // streamed operand, row stride = K
  int nfg;               // feature groups (RES_A): grid = nfg * stripes
  const float* actS;
  const float* amax;
  int amaxIdx, sInIdx, sOutIdx;
  const float* bias;
  int8_t* out8;          // EPI2
  int ldOut;
  const float* xorg;     // EPI0
  const float* g1s; const float* a2s8; const float* b2s;
  int8_t* X1q; int8_t* A2;
  const float* g2s9;     // EPI3
  const int8_t* X1qIn;
  float* outF;
  const int8_t* lutG;    // EPI2
};

template<int EPI, int KT, bool RESB, int T>
__launch_bounds__(256, 2)
__global__ void gemm_wres(WresParams p) {
  const int tid  = threadIdx.x;
  const int wid  = tid >> 6;
  const int lane = tid & 63;
  const int quad = lane >> 4, l15 = lane & 15, l31 = lane & 31;
  const int K  = KT * 64;
  const int bx = blockIdx.x;

  // bank-replicated GELU LUT: lutR[qh][c] (u32, 4 int8 entries packed);
  // lane reads column (lane&31) -> bank == lane&31 -> conflict-free.
  __shared__ uint32_t lutR[64*32];
  if constexpr (EPI == 2) {
    if (tid < 64) {
      const uint8_t* lg = (const uint8_t*)p.lutG + tid*4;
      uint32_t v = (uint32_t)lg[0] | ((uint32_t)lg[1] << 8) |
                   ((uint32_t)lg[2] << 16) | ((uint32_t)lg[3] << 24);
      #pragma unroll
      for (int c = 0; c < 32; ++c) lutR[tid*32 + c] = v;
    }
    __syncthreads();
  }

  // resident rows for this wave (RESB: m-cols j0; else feature rows i0)
  const int fg  = RESB ? 0 : (bx % p.nfg);
  const int i0w = RESB ? (wid*64) : (fg*256 + wid*64);

  i32x4 res[KT][4];
  {
    const int8_t* rbase = p.Wres + (long)(i0w + l15)*K + quad*16;
    #pragma unroll
    for (int f = 0; f < 4; ++f)
      #pragma unroll
      for (int kk = 0; kk < KT; ++kk)
        res[kk][f] = *(const i32x4*)(rbase + (long)f*16*K + kk*64);
  }

  // streamed rows: row0 .. row0 + T*64
  const long row0 = RESB ? (long)bx*(T*64) : (long)(bx / p.nfg)*(T*64);
  const int8_t* sbase = p.Astr + (row0 + l15)*K + quad*16;

  // epilogue constants (hoisted)
  const float sW  = p.amax[p.amaxIdx] / 127.f + 1e-8f;
  const float sAB = p.actS[p.sInIdx] * sW;
  float c1f = 0.f, cA = 0.f, cB = 0.f;
  if constexpr (EPI == 0) { c1f = sAB / p.actS[1]; cA = 1.f / p.actS[8]; cB = p.actS[1]; }
  if constexpr (EPI == 2) { c1f = sAB / p.actS[p.sOutIdx]; cB = p.actS[p.sOutIdx]; }
  if constexpr (EPI == 3) { c1f = sAB / p.actS[3]; cA = p.actS[8] / p.actS[9]; cB = p.actS[9]; }

  i32x4 s0[4], s1[4];
  #pragma unroll
  for (int f = 0; f < 4; ++f)
    s0[f] = *(const i32x4*)(sbase + (long)(f*16)*K);

#define LDSTREAM(dst, tOff, kkv) \
  _Pragma("unroll") \
  for (int f = 0; f < 4; ++f) \
    dst[f] = *(const i32x4*)(sbase + ((long)(tOff) + f*16)*K + (kkv)*64);

#define DOMFMA(cur, kkv) \
  _Pragma("unroll") \
  for (int i_ = 0; i_ < 4; ++i_) \
    _Pragma("unroll") \
    for (int j_ = 0; j_ < 4; ++j_) { \
      if constexpr (RESB) \
        acc[i_][j_] = __builtin_amdgcn_mfma_i32_16x16x64_i8(cur[i_], res[kkv][j_], acc[i_][j_], 0, 0, 0); \
      else \
        acc[i_][j_] = __builtin_amdgcn_mfma_i32_16x16x64_i8(res[kkv][i_], cur[j_], acc[i_][j_], 0, 0, 0); }

  for (int tl = 0; tl < T; ++tl) {
    const i32x4 zero = {0, 0, 0, 0};
    i32x4 acc[4][4];
    #pragma unroll
    for (int i = 0; i < 4; ++i)
      #pragma unroll
      for (int j = 0; j < 4; ++j) acc[i][j] = zero;

    #pragma unroll
    for (int kk = 0; kk < KT; ++kk) {      // KT even: parity consistent across tiles
      if ((kk & 1) == 0) {
        if (kk + 1 < KT)     { LDSTREAM(s1, (long)tl*64, kk + 1) }
        else if (tl + 1 < T) { LDSTREAM(s1, (long)(tl + 1)*64, 0) }
        DOMFMA(s0, kk)
      } else {
        if (kk + 1 < KT)     { LDSTREAM(s0, (long)tl*64, kk + 1) }
        else if (tl + 1 < T) { LDSTREAM(s0, (long)(tl + 1)*64, 0) }
        DOMFMA(s1, kk)
      }
    }

    // ---- epilogue (C/D layout 16x16: col=lane&15, row=quad*4+reg) ----
    if constexpr (EPI == 0) {
      // rows = streamed g=b*768+d, cols = resident m (guard <196)
      const long g0 = row0 + (long)tl*64;
      const int b = (int)(g0 / D_);
      const int dbase = (int)(g0 - (long)b*D_);
      #pragma unroll
      for (int ii = 0; ii < 4; ++ii) {
        const int d = dbase + ii*16 + quad*4;
        const float4 g1s4 = *(const float4*)(p.g1s + d);
        const float4 a2s4 = *(const float4*)(p.a2s8 + d);
        const float4 b2s4 = *(const float4*)(p.b2s + d);
        #pragma unroll
        for (int jj = 0; jj < 4; ++jj) {
          const int m = i0w + jj*16 + l15;
          if (m < N_) {
            const float c2 = p.bias[m] / cB;
            const long tok = (long)b*N_ + m;
            const float4 xo = *(const float4*)(p.xorg + tok*D_ + d);
            uint32_t pk8 = 0, pk2 = 0;
            #pragma unroll
            for (int r = 0; r < 4; ++r) {
              float accf = (float)acc[ii][jj][r];
              float q1 = rclipf(fmaf(accf, c1f, c2));
              float q8 = rclipf(fmaf(q1, ((const float*)&g1s4)[r],
                                     ((const float*)&xo)[r] * cA));
              float q2 = rclipf(fmaf(q8, ((const float*)&a2s4)[r],
                                     ((const float*)&b2s4)[r]));
              pk8 |= ((uint32_t)(uint8_t)(int8_t)(int)q8) << (8*r);
              pk2 |= ((uint32_t)(uint8_t)(int8_t)(int)q2) << (8*r);
            }
            *(uint32_t*)(p.X1q + tok*D_ + d) = pk8;
            *(uint32_t*)(p.A2  + tok*D_ + d) = pk2;
          }
        }
      }
    } else if constexpr (EPI == 2) {
      const long t0 = row0 + (long)tl*64;
      #pragma unroll
      for (int ii = 0; ii < 4; ++ii) {
        const int i = i0w + ii*16 + quad*4;
        const float4 b4 = *(const float4*)(p.bias + i);
        float c2[4];
        #pragma unroll
        for (int r = 0; r < 4; ++r) c2[r] = ((const float*)&b4)[r] / cB;
        #pragma unroll
        for (int jj = 0; jj < 4; ++jj) {
          const int j = (int)t0 + jj*16 + l15;
          uint32_t pk = 0;
          #pragma unroll
          for (int r = 0; r < 4; ++r) {
            int q5 = (int)rclipf(fmaf((float)acc[ii][jj][r], c1f, c2[r])) + 128;
            uint32_t v = lutR[(q5 >> 2)*32 + l31];
            pk |= ((v >> ((q5 & 3)*8)) & 0xffu) << (8*r);
          }
          *(uint32_t*)(p.out8 + (long)j*p.ldOut + i) = pk;
        }
      }
    } else {  // EPI == 3
      const long t0 = row0 + (long)tl*64;
      #pragma unroll
      for (int ii = 0; ii < 4; ++ii) {
        const int i = i0w + ii*16 + quad*4;
        const float4 b4 = *(const float4*)(p.bias + i);
        const float4 g4 = *(const float4*)(p.g2s9 + i);
        float c2[4];
        #pragma unroll
        for (int r = 0; r < 4; ++r) c2[r] = ((const float*)&b4)[r] / p.actS[3];
        #pragma unroll
        for (int jj = 0; jj < 4; ++jj) {
          const int j = (int)t0 + jj*16 + l15;
          const uint32_t pk8 = *(const uint32_t*)(p.X1qIn + (long)j*D_ + i);
          float4 o;
          #pragma unroll
          for (int r = 0; r < 4; ++r) {
            float q3 = rclipf(fmaf((float)acc[ii][jj][r], c1f, c2[r]));
            float q8 = (float)(int8_t)(uint8_t)(pk8 >> (8*r));
            float q9 = rclipf(fmaf(q3, ((const float*)&g4)[r], q8 * cA));
            ((float*)&o)[r] = cB * q9;
          }
          *(float4*)(p.outF + (long)j*D_ + i) = o;
        }
      }
    }
  }
#undef LDSTREAM
#undef DOMFMA
}

// ---------------- host launch ----------------
extern "C" void kernel_launch(void* const* d_in, const int* in_sizes, int n_in,
                              void* d_out, int out_size, void* d_ws, size_t ws_size,
                              hipStream_t stream) {
  (void)in_sizes; (void)n_in; (void)out_size; (void)ws_size;
  const float* x    = (const float*)d_in[0];
  const float* n1a  = (const float*)d_in[1];
  const float* n1b  = (const float*)d_in[2];
  const float* attw = (const float*)d_in[3];
  const float* attb = (const float*)d_in[4];
  const float* g1   = (const float*)d_in[5];
  const float* n2a  = (const float*)d_in[6];
  const float* n2b  = (const float*)d_in[7];
  const float* w1vt = (const float*)d_in[8];
  const float* b1vt = (const float*)d_in[9];
  const float* w1u  = (const float*)d_in[10];
  const float* b1u  = (const float*)d_in[11];
  const float* w2vt = (const float*)d_in[12];
  const float* b2vt = (const float*)d_in[13];
  const float* w2u  = (const float*)d_in[14];
  const float* b2u  = (const float*)d_in[15];
  const float* g2   = (const float*)d_in[16];
  const float* actS = (const float*)d_in[17];
  float* out = (float*)d_out;
  char* ws = (char*)d_ws;

  float*  amax = (float*)(ws + OFF_AMAX);
  int8_t* LUTG = (int8_t*)(ws + OFF_LUT);
  float*  qvec = (float*)(ws + OFF_QVEC);
  int8_t* WQA  = (int8_t*)(ws + OFF_WQA);
  int8_t* W1VT = (int8_t*)(ws + OFF_W1VT);
  int8_t* W1U  = (int8_t*)(ws + OFF_W1U);
  int8_t* W2VT = (int8_t*)(ws + OFF_W2VT);
  int8_t* W2U  = (int8_t*)(ws + OFF_W2U);
  int8_t* X1Q  = (int8_t*)(ws + OFF_X1Q);
  int8_t* A4   = (int8_t*)(ws + OFF_A4);
  int8_t* A7   = (int8_t*)(ws + OFF_A7);
  int8_t* A0T  = (int8_t*)(ws + OFF_A0T);
  int8_t* A2   = (int8_t*)(ws + OFF_A2);
  int8_t* A6   = (int8_t*)(ws + OFF_A6);

  hipMemsetAsync(amax, 0, 64, stream);
  absmax_k<<<dim3(32, 9), 256, 0, stream>>>(n1a, attw, g1, n2a, w1vt, w1u, w2vt, w2u, g2, amax);
  prep_vec_k<<<1, 768, 0, stream>>>(n1a, n1b, g1, n2a, n2b, g2, amax, actS, qvec, LUTG);
  quant_all_k<<<dim3(1152, 5), 256, 0, stream>>>(w1vt, w1u, w2vt, w2u, attw, amax,
                                                 W1VT, W1U, W2VT, W2U, WQA);
  stageA_k<<<dim3(12, 4, 128), 256, 0, stream>>>(x, qvec, qvec + 768, A0T);

  // attn (weight-resident, barrier-free): stream rows g=b*768+d of A0T,
  // WQA (m x 256) resident in VGPRs (wave wid owns m in [wid*64, wid*64+64)).
  // 512 blocks x 3 tiles x 64 rows = 98304 = 128*768. 512 = 256 CU x 2.
  WresParams pa = {};
  pa.Wres = WQA; pa.Astr = A0T;
  pa.actS = actS; pa.amax = amax; pa.amaxIdx = 1; pa.sInIdx = 0;
  pa.bias = attb; pa.xorg = x;
  pa.g1s = qvec + 1536; pa.a2s8 = qvec + 2304; pa.b2s = qvec + 3072;
  pa.X1q = X1Q; pa.A2 = A2;
  gemm_wres<0, 4, true, 3><<<dim3(512), 256, 0, stream>>>(pa);

  // fc1_VT (K=768, too big for register residency): old LDS path
  GemmParams p1 = {};
  p1.A = W1VT; p1.W = A2; p1.K = D_; p1.MT = R_/128; p1.NT = TOK/128;
  p1.actS = actS; p1.amax = amax; p1.amaxIdx = 4; p1.sInIdx = 2; p1.sOutIdx = 4;
  p1.bias = b1vt; p1.out8 = A4; p1.ldOut = R_;
  gemm_i8<1><<<dim3((R_/128)*(TOK/128)), 256, 0, stream>>>(p1);

  // fc1_U (weight-resident): W1U rows resident (12 groups of 256 feat),
  // stream A4 tokens; GELU via bank-replicated LUT. 12 x 98 stripes x 4 tiles.
  WresParams p2 = {};
  p2.Wres = W1U; p2.Astr = A4; p2.nfg = 12;
  p2.actS = actS; p2.amax = amax; p2.amaxIdx = 5; p2.sInIdx = 4; p2.sOutIdx = 5;
  p2.bias = b1u; p2.out8 = A6; p2.ldOut = H_; p2.lutG = LUTG;
  gemm_wres<2, 6, false, 4><<<dim3(12*98), 256, 0, stream>>>(p2);

  // fc2_VT (K=3072): old LDS path
  GemmParams p3 = {};
  p3.A = W2VT; p3.W = A6; p3.K = H_; p3.MT = R_/128; p3.NT = TOK/128;
  p3.actS = actS; p3.amax = amax; p3.amaxIdx = 6; p3.sInIdx = 6; p3.sOutIdx = 7;
  p3.bias = b2vt; p3.out8 = A7; p3.ldOut = R_;
  gemm_i8<1><<<dim3((R_/128)*(TOK/128)), 256, 0, stream>>>(p3);

  // fc2_U (weight-resident): W2U rows resident (3 groups of 256 feat),
  // stream A7 tokens. 3 x 196 stripes x 2 tiles.
  WresParams p4 = {};
  p4.Wres = W2U; p4.Astr = A7; p4.nfg = 3;
  p4.actS = actS; p4.amax = amax; p4.amaxIdx = 7; p4.sInIdx = 7;
  p4.bias = b2u; p4.g2s9 = qvec + 3840; p4.X1qIn = X1Q; p4.outF = out;
  gemm_wres<3, 6, false, 2><<<dim3(3*196), 256, 0, stream>>>(p4);
}

// Round 2
// 559.412 us; speedup vs baseline: 1.0079x; 1.0079x over previous
//
#include <hip/hip_runtime.h>
#include <cstdint>
#include <cmath>

// Problem dims
#define B_   128
#define N_   196
#define D_   768
#define H_   3072
#define R_   384
#define TOK  (B_*N_)      // 25088

typedef int i32x4 __attribute__((ext_vector_type(4)));

// async global->LDS, 16B per lane; LDS dest = wave-uniform base + lane*16
#define GLDS16(g, l) __builtin_amdgcn_global_load_lds( \
    (const __attribute__((address_space(1))) void*)(g), \
    (__attribute__((address_space(3))) void*)(l), 16, 0, 0)

// s_waitcnt imm (gfx9): vmcnt[3:0], expcnt[6:4]=7, lgkmcnt[11:8]=15
#define WAITV4() __builtin_amdgcn_s_waitcnt(0xF74)   // vmcnt(4)
#define WAITV0() __builtin_amdgcn_s_waitcnt(0xF70)   // vmcnt(0)
#define BARRIER() do { __asm__ volatile("" ::: "memory"); \
                       __builtin_amdgcn_s_barrier(); \
                       __asm__ volatile("" ::: "memory"); } while (0)

// ---------------- workspace layout (bytes) ----------------
#define OFF_AMAX   0L
#define OFF_LUT    512L                  // 256-entry int8 GELU LUT
#define OFF_QVEC   1024L                 // 6 x 768 fp32 precomputed epilogue vectors
#define OFF_WQA    (32L*1024)            // attn weight int8 padded [256][256]
#define OFF_W1VT   (128L*1024)           // [384][768]
#define OFF_W1U    (512L*1024)           // [3072][384]
#define OFF_W2VT   (2L*1024*1024)        // [384][3072]
#define OFF_W2U    (3328L*1024)          // [768][384]
#define OFF_X1Q    (4L*1024*1024)        // int8 [25088][768]
#define OFF_A4     (24L*1024*1024)       // int8 [25088][384]
#define OFF_A7     (34L*1024*1024)       // int8 [25088][384]
#define OFF_A0T    (44L*1024*1024)       // int8 [128][768][256] (dead after attn)
#define OFF_A2     (68L*1024*1024)       // int8 [25088][768]    (dead after fc1_vt)
#define OFF_A6     (44L*1024*1024)       // int8 [25088][3072]   (overlays A0T+A2)

__device__ __forceinline__ float rclipf(float v) {
  // clip(round_half_even(v), -128, 127) ; matches jnp.clip(jnp.round(x),-n,n-1)
  return fminf(fmaxf(rintf(v), -128.f), 127.f);
}

// ---------------- absmax over 9 weight tensors ----------------
__global__ void absmax_k(const float* p0, const float* p1, const float* p2,
                         const float* p3, const float* p4, const float* p5,
                         const float* p6, const float* p7, const float* p8,
                         float* amax) {
  int tsel = blockIdx.y;
  const float* src; int n;
  switch (tsel) {
    case 0: src = p0; n = 768;     break;  // norm1_a
    case 1: src = p1; n = N_*N_;   break;  // attn_w
    case 2: src = p2; n = 768;     break;  // gamma1
    case 3: src = p3; n = 768;     break;  // norm2_a
    case 4: src = p4; n = R_*D_;   break;  // fc1_vt_w
    case 5: src = p5; n = H_*R_;   break;  // fc1_u_w
    case 6: src = p6; n = R_*H_;   break;  // fc2_vt_w
    case 7: src = p7; n = D_*R_;   break;  // fc2_u_w
    default: src = p8; n = 768;    break;  // gamma2
  }
  float m = 0.f;
  for (int i = blockIdx.x*blockDim.x + threadIdx.x; i < n; i += gridDim.x*blockDim.x)
    m = fmaxf(m, fabsf(src[i]));
  #pragma unroll
  for (int off = 32; off > 0; off >>= 1)
    m = fmaxf(m, __shfl_down(m, off));
  if ((threadIdx.x & 63) == 0)
    atomicMax((int*)(amax + tsel), __float_as_int(m));
}

// ---------------- precompute epilogue vectors + GELU LUT (1 block, 768 thr) ----------------
__global__ void prep_vec_k(const float* n1a, const float* n1b, const float* g1,
                           const float* n2a, const float* n2b, const float* g2,
                           const float* amax, const float* actS, float* dst,
                           int8_t* lut) {
  int i = threadIdx.x;  // 768
  float s0 = actS[0], s1 = actS[1], s2 = actS[2], s3 = actS[3];
  float s8 = actS[8], s9 = actS[9];
  float sw;
  sw = amax[0]/127.f + 1e-8f; float qn1a = sw * rclipf(n1a[i]/sw);
  dst[i]        = qn1a / s0;
  dst[768+i]    = n1b[i] / s0;
  sw = amax[2]/127.f + 1e-8f; float qg1 = sw * rclipf(g1[i]/sw);
  dst[1536+i]   = (s1 * qg1) / s8;
  sw = amax[3]/127.f + 1e-8f; float qn2a = sw * rclipf(n2a[i]/sw);
  dst[2304+i]   = (s8 * qn2a) / s2;
  dst[3072+i]   = n2b[i] / s2;
  sw = amax[8]/127.f + 1e-8f; float qg2 = sw * rclipf(g2[i]/sw);
  dst[3840+i]   = (s3 * qg2) / s9;
  if (i < 256) {
    float s5 = actS[5], s6 = actS[6];
    float v5 = s5 * (float)(i - 128);
    float g  = 0.5f * v5 * (1.f + erff(v5 * 0.70710678118654752f));
    lut[i] = (int8_t)(int)rclipf(g / s6);
  }
}

// ---------------- quantize all 5 matmul weights ----------------
__global__ void quant_all_k(const float* w1vt, const float* w1u, const float* w2vt,
                            const float* w2u, const float* attw, const float* amax,
                            int8_t* W1VT, int8_t* W1U, int8_t* W2VT, int8_t* W2U,
                            int8_t* WQA) {
  int sel = blockIdx.y;
  const float* src; int8_t* dst; int n; float am;
  switch (sel) {
    case 0: src = w1vt; dst = W1VT; n = R_*D_;  am = amax[4]; break;
    case 1: src = w1u;  dst = W1U;  n = H_*R_;  am = amax[5]; break;
    case 2: src = w2vt; dst = W2VT; n = R_*H_;  am = amax[6]; break;
    case 3: src = w2u;  dst = W2U;  n = D_*R_;  am = amax[7]; break;
    default: src = attw; dst = WQA; n = 65536;  am = amax[1]; break;
  }
  float s = am / 127.f + 1e-8f;
  if (sel < 4) {
    for (int i = blockIdx.x*blockDim.x + threadIdx.x; i < n; i += gridDim.x*blockDim.x)
      dst[i] = (int8_t)(int)rclipf(src[i] / s);
  } else {
    for (int i = blockIdx.x*blockDim.x + threadIdx.x; i < n; i += gridDim.x*blockDim.x) {
      int m = i >> 8, nn = i & 255;
      int8_t q = 0;
      if (m < N_ && nn < N_) q = (int8_t)(int)rclipf(attw[m*N_ + nn] / s);
      dst[i] = q;
    }
  }
}

// ---------------- stage A: norm1 affine + act-quant, transposed to A0T[b][d][n256] ----------------
__global__ void stageA_k(const float* __restrict__ x, const float* __restrict__ n1as,
                         const float* __restrict__ n1bs, int8_t* __restrict__ A0T) {
  __shared__ int8_t ldsT[64*68];
  const int dt = blockIdx.x;
  const int nt = blockIdx.y;
  const int b  = blockIdx.z;
  const int d0 = dt*64, n0 = nt*64;
  const int tid = threadIdx.x;
  const int dc = tid & 63, nr4 = tid >> 6;
  const float qa = n1as[d0 + dc];
  const float bb = n1bs[d0 + dc];
  #pragma unroll 4
  for (int it = 0; it < 16; ++it) {
    int nl = nr4 + it*4;
    int n = n0 + nl;
    int8_t q = 0;
    if (n < N_) {
      float v = fmaf(x[((long)b*N_ + n)*D_ + d0 + dc], qa, bb);
      q = (int8_t)(int)rclipf(v);
    }
    ldsT[dc*68 + nl] = q;
  }
  __syncthreads();
  const int k = tid & 15, dr = tid >> 4;
  #pragma unroll
  for (int it = 0; it < 4; ++it) {
    int d = dr + it*16;
    uint32_t v = *(const uint32_t*)(&ldsT[d*68 + k*4]);
    *(uint32_t*)(&A0T[(long)b*(D_*256) + (long)(d0+d)*256 + n0 + k*4]) = v;
  }
}

// ---------------- shared param struct ----------------
struct GemmParams {
  const int8_t* A;
  const int8_t* W;
  int K, MT, NT;
  long batchStrideA;
  const float* actS;
  const float* amax;
  int amaxIdx, sInIdx, sOutIdx, sOut2Idx;
  const float* bias;     // indexed by i (EPI 1/2/3) or j (EPI 0)
  int8_t* out8;
  int ldOut;
  const float* xorg;     // EPI0
  const float* g1s;
  const float* a2s8;
  const float* b2s;
  int8_t* X1q;
  int8_t* A2;
  const float* g2s9;     // EPI3
  const int8_t* X1qIn;
  float* outF;
  const int8_t* lutG;    // EPI2
};

// ---------------- attn GEMM (round-0 verified 128x128 2-phase, EPI0 only) ----------------
template<int EPI>
__launch_bounds__(256, 4)
__global__ void gemm_i8(GemmParams p) {
  __shared__ __align__(16) int8_t lsA[2][128][64];
  __shared__ __align__(16) int8_t lsB[2][128][64];
  const int K  = p.K;
  const int bx = blockIdx.x;
  const int mt = bx % p.MT;
  const int nt = bx / p.MT;
  const int t    = threadIdx.x;
  const int wid  = t >> 6;
  const int lane = t & 63;
  const int wm = wid & 1, wn = wid >> 1;
  const int quad = lane >> 4, l15 = lane & 15;

  const int8_t* Abase = p.A + (long)blockIdx.y * p.batchStrideA + (long)mt*128*K;
  const int8_t* Wbase = p.W + (long)nt*128*K;

  const int8_t* Ab = Abase + (long)(t >> 2)*K + (t & 3)*16;
  const int8_t* Bb = Wbase + (long)(t >> 2)*K + (t & 3)*16;
  const long half = 64L * K;

  auto issue = [&](int kt) {
    const int buf = kt & 1;
    const long k = (long)kt << 6;
    GLDS16(Ab + k,        &lsA[buf][0][0]  + t*16);
    GLDS16(Ab + half + k, &lsA[buf][64][0] + t*16);
    GLDS16(Bb + k,        &lsB[buf][0][0]  + t*16);
    GLDS16(Bb + half + k, &lsB[buf][64][0] + t*16);
  };

  const i32x4 zero = {0, 0, 0, 0};
  i32x4 acc[4][4];
  #pragma unroll
  for (int i = 0; i < 4; ++i)
    #pragma unroll
    for (int j = 0; j < 4; ++j) acc[i][j] = zero;

  const int KT = K >> 6;
  issue(0);
  for (int kt = 0; kt < KT; ++kt) {
    const int cur = kt & 1;
    if (kt + 1 < KT) { issue(kt + 1); WAITV4(); }
    else             { WAITV0(); }
    BARRIER();
    i32x4 af[4], bf[4];
    #pragma unroll
    for (int i = 0; i < 4; ++i)
      af[i] = *(const i32x4*)(&lsA[cur][wm*64 + i*16 + l15][quad*16]);
    #pragma unroll
    for (int j = 0; j < 4; ++j)
      bf[j] = *(const i32x4*)(&lsB[cur][wn*64 + j*16 + l15][quad*16]);
    #pragma unroll
    for (int i = 0; i < 4; ++i)
      #pragma unroll
      for (int j = 0; j < 4; ++j)
        acc[i][j] = __builtin_amdgcn_mfma_i32_16x16x64_i8(af[i], bf[j], acc[i][j], 0, 0, 0);
    BARRIER();
  }

  // ---- EPI0 epilogue: attn + gamma1 + residual + norm2 + act3 ----
  const float sW  = p.amax[p.amaxIdx] / 127.f + 1e-8f;
  const float sAB = p.actS[p.sInIdx] * sW;
  const int i0 = mt*128 + wm*64;
  const int j0 = nt*128 + wn*64;

  #pragma unroll
  for (int ii = 0; ii < 4; ++ii) {
    const int i = i0 + ii*16 + quad*4;   // d (0..767)
    const float c1     = sAB / p.actS[1];
    const float inv_s8 = 1.f / p.actS[8];
    const float4 g1s4 = *(const float4*)(p.g1s + i);
    const float4 a2s4 = *(const float4*)(p.a2s8 + i);
    const float4 b2s4 = *(const float4*)(p.b2s + i);
    #pragma unroll
    for (int jj = 0; jj < 4; ++jj) {
      const int j = j0 + jj*16 + l15;    // m patch
      if (j < N_) {
        const float c2 = p.bias[j] / p.actS[1];
        const long tok = (long)blockIdx.y * N_ + j;
        const float4 xo = *(const float4*)(p.xorg + tok*D_ + i);
        uint32_t pk8 = 0, pk2 = 0;
        #pragma unroll
        for (int r = 0; r < 4; ++r) {
          float accf = (float)acc[ii][jj][r];
          float q1 = rclipf(fmaf(accf, c1, c2));
          float q8 = rclipf(fmaf(q1, ((const float*)&g1s4)[r],
                                 ((const float*)&xo)[r] * inv_s8));
          float q2 = rclipf(fmaf(q8, ((const float*)&a2s4)[r],
                                 ((const float*)&b2s4)[r]));
          pk8 |= ((uint32_t)(uint8_t)(int8_t)(int)q8) << (8*r);
          pk2 |= ((uint32_t)(uint8_t)(int8_t)(int)q2) << (8*r);
        }
        *(uint32_t*)(p.X1q + tok*D_ + i) = pk8;
        *(uint32_t*)(p.A2  + tok*D_ + i) = pk2;
      }
    }
  }
}

// ---------------- 8-phase i8 GEMM (T3+T4+T5 port): 512 thr, BMxBN = (MFR*32)x256 ----------------
// Triple-buffered LDS, depth-2 K-tile prefetch, counted vmcnt once per K-tile,
// 4 phases per K-tile: {ds-read subtile | 1 GLDS issue | barrier | setprio(1)
// MFMA quadrant setprio(0) | barrier}. EPI: 1=quant, 2=quant+GELU LUT, 3=final fp32.
template<int EPI, int MFR, int NLD, int K>
__launch_bounds__(512, 2)
__global__ void gemm_ph(GemmParams p) {
  constexpr int BM = MFR * 32;        // 256 or 128
  constexpr int KT = K / 64;
  constexpr int HM = MFR / 2;
  __shared__ __align__(16) int8_t lsA[3][BM][64];
  __shared__ __align__(16) int8_t lsB[3][256][64];
  __shared__ uint32_t lutR[(EPI == 2) ? 64*32 : 4];  // bank-replicated GELU LUT

  const int t    = threadIdx.x;
  const int wid  = t >> 6;
  const int lane = t & 63;
  const int wm = wid & 1, wn = wid >> 1;              // waves 2 x 4
  const int quad = lane >> 4, l15 = lane & 15, l31 = lane & 31;

  if constexpr (EPI == 2) {
    if (t < 64) {
      const uint8_t* lg = (const uint8_t*)p.lutG + t*4;
      uint32_t v = (uint32_t)lg[0] | ((uint32_t)lg[1] << 8) |
                   ((uint32_t)lg[2] << 16) | ((uint32_t)lg[3] << 24);
      #pragma unroll
      for (int c = 0; c < 32; ++c) lutR[t*32 + c] = v;
    }
    __syncthreads();
  }

  // XCD-aware swizzle (T1) when grid divisible by 8
  int bx = blockIdx.x;
  { const int nwg = gridDim.x;
    if ((nwg & 7) == 0) { const int c = nwg >> 3; bx = (bx & 7)*c + (bx >> 3); } }
  const int mt = bx % p.MT;
  const int nt = bx / p.MT;

  const int8_t* Ab = p.A + (long)mt*BM*K  + (long)(t >> 2)*K + (t & 3)*16;
  const int8_t* Bb = p.W + (long)nt*256*K + (long)(t >> 2)*K + (t & 3)*16;

  // one 16B GLDS per thread per load-slot; A = MFR/4 slots, B = 2 slots
  auto issue1 = [&](int buf, int kt, int ld) {
    const long kOff = (long)kt * 64;
    if constexpr (MFR == 8) {
      if (ld < 2) GLDS16(Ab + (long)ld*128*K + kOff,
                         &lsA[0][0][0] + (long)buf*(BM*64) + ld*8192 + t*16);
      else        GLDS16(Bb + (long)(ld-2)*128*K + kOff,
                         &lsB[0][0][0] + (long)buf*(256*64) + (ld-2)*8192 + t*16);
    } else {
      if (ld == 0) GLDS16(Ab + kOff,
                          &lsA[0][0][0] + (long)buf*(BM*64) + t*16);
      else         GLDS16(Bb + (long)(ld-1)*128*K + kOff,
                          &lsB[0][0][0] + (long)buf*(256*64) + (ld-1)*8192 + t*16);
    }
  };

  const i32x4 zero = {0, 0, 0, 0};
  i32x4 acc[MFR][4];
  #pragma unroll
  for (int i = 0; i < MFR; ++i)
    #pragma unroll
    for (int j = 0; j < 4; ++j) acc[i][j] = zero;

  // prologue: tiles 0 and 1 fully staged/in-flight
  #pragma unroll
  for (int ld = 0; ld < NLD; ++ld) issue1(0, 0, ld);
  #pragma unroll
  for (int ld = 0; ld < NLD; ++ld) issue1(1, 1, ld);
  __builtin_amdgcn_s_waitcnt(0xF70 | NLD);   // tile 0 landed, tile 1 in flight
  BARRIER();

  int bufR = 0, bufW = 2;
  #pragma unroll 1
  for (int kt = 0; kt < KT; ++kt) {
    const bool iss = (kt + 2 < KT);
    i32x4 af[MFR], bf[4];

    // ---- phase 0: af lower + bf[0:2]; MFMA quadrant (lo, left) ----
    #pragma unroll
    for (int i = 0; i < HM; ++i)
      af[i] = *(const i32x4*)(&lsA[bufR][wm*(BM/2) + i*16 + l15][quad*16]);
    bf[0] = *(const i32x4*)(&lsB[bufR][wn*64 +  0 + l15][quad*16]);
    bf[1] = *(const i32x4*)(&lsB[bufR][wn*64 + 16 + l15][quad*16]);
    if (iss) issue1(bufW, kt + 2, 0);
    BARRIER();
    __builtin_amdgcn_s_setprio(1);
    #pragma unroll
    for (int i = 0; i < HM; ++i)
      #pragma unroll
      for (int j = 0; j < 2; ++j)
        acc[i][j] = __builtin_amdgcn_mfma_i32_16x16x64_i8(af[i], bf[j], acc[i][j], 0, 0, 0);
    __builtin_amdgcn_s_setprio(0);
    BARRIER();

    // ---- phase 1: af upper; MFMA quadrant (hi, left) ----
    #pragma unroll
    for (int i = HM; i < MFR; ++i)
      af[i] = *(const i32x4*)(&lsA[bufR][wm*(BM/2) + i*16 + l15][quad*16]);
    if (iss && 1 < NLD) issue1(bufW, kt + 2, 1);
    BARRIER();
    __builtin_amdgcn_s_setprio(1);
    #pragma unroll
    for (int i = HM; i < MFR; ++i)
      #pragma unroll
      for (int j = 0; j < 2; ++j)
        acc[i][j] = __builtin_amdgcn_mfma_i32_16x16x64_i8(af[i], bf[j], acc[i][j], 0, 0, 0);
    __builtin_amdgcn_s_setprio(0);
    BARRIER();

    // ---- phase 2: bf[2:4]; MFMA quadrant (lo, right) ----
    bf[2] = *(const i32x4*)(&lsB[bufR][wn*64 + 32 + l15][quad*16]);
    bf[3] = *(const i32x4*)(&lsB[bufR][wn*64 + 48 + l15][quad*16]);
    if (iss && 2 < NLD) issue1(bufW, kt + 2, 2);
    BARRIER();
    __builtin_amdgcn_s_setprio(1);
    #pragma unroll
    for (int i = 0; i < HM; ++i)
      #pragma unroll
      for (int j = 2; j < 4; ++j)
        acc[i][j] = __builtin_amdgcn_mfma_i32_16x16x64_i8(af[i], bf[j], acc[i][j], 0, 0, 0);
    __builtin_amdgcn_s_setprio(0);
    BARRIER();

    // ---- phase 3: MFMA quadrant (hi, right); counted vmcnt for next tile ----
    if (iss && 3 < NLD) issue1(bufW, kt + 2, 3);
    BARRIER();
    __builtin_amdgcn_s_setprio(1);
    #pragma unroll
    for (int i = HM; i < MFR; ++i)
      #pragma unroll
      for (int j = 2; j < 4; ++j)
        acc[i][j] = __builtin_amdgcn_mfma_i32_16x16x64_i8(af[i], bf[j], acc[i][j], 0, 0, 0);
    __builtin_amdgcn_s_setprio(0);
    if (iss) __builtin_amdgcn_s_waitcnt(0xF70 | NLD);  // tile kt+1 landed; kt+2 in flight
    else     WAITV0();
    BARRIER();

    bufR = (bufR == 2) ? 0 : bufR + 1;
    bufW = (bufW == 2) ? 0 : bufW + 1;
  }

  // ---- epilogue ---- C/D layout (16x16): col=lane&15 (j), row=quad*4+r (i)
  const float sW  = p.amax[p.amaxIdx] / 127.f + 1e-8f;
  const float sAB = p.actS[p.sInIdx] * sW;
  const int i0 = mt*BM + wm*(BM/2);
  const int j0 = nt*256 + wn*64;

  #pragma unroll
  for (int ii = 0; ii < MFR; ++ii) {
    const int i = i0 + ii*16 + quad*4;
    if constexpr (EPI == 1) {
      const float sO = p.actS[p.sOutIdx];
      const float c1 = sAB / sO;
      const float4 b4 = *(const float4*)(p.bias + i);
      float c2[4];
      #pragma unroll
      for (int r = 0; r < 4; ++r) c2[r] = ((const float*)&b4)[r] / sO;
      #pragma unroll
      for (int jj = 0; jj < 4; ++jj) {
        const int j = j0 + jj*16 + l15;
        uint32_t pk = 0;
        #pragma unroll
        for (int r = 0; r < 4; ++r) {
          float q = rclipf(fmaf((float)acc[ii][jj][r], c1, c2[r]));
          pk |= ((uint32_t)(uint8_t)(int8_t)(int)q) << (8*r);
        }
        *(uint32_t*)(p.out8 + (long)j*p.ldOut + i) = pk;
      }
    } else if constexpr (EPI == 2) {
      const float s5v = p.actS[p.sOutIdx];
      const float c1 = sAB / s5v;
      const float4 b4 = *(const float4*)(p.bias + i);
      float c2[4];
      #pragma unroll
      for (int r = 0; r < 4; ++r) c2[r] = ((const float*)&b4)[r] / s5v;
      #pragma unroll
      for (int jj = 0; jj < 4; ++jj) {
        const int j = j0 + jj*16 + l15;
        uint32_t pk = 0;
        #pragma unroll
        for (int r = 0; r < 4; ++r) {
          int q5 = (int)rclipf(fmaf((float)acc[ii][jj][r], c1, c2[r])) + 128;
          uint32_t v = lutR[(q5 >> 2)*32 + l31];
          pk |= ((v >> ((q5 & 3)*8)) & 0xffu) << (8*r);
        }
        *(uint32_t*)(p.out8 + (long)j*p.ldOut + i) = pk;
      }
    } else {  // EPI == 3: block act4 + gamma2 + residual(X1q) + add_2 -> fp32
      const float s3v = p.actS[3], s9v = p.actS[9];
      const float c1  = sAB / s3v;
      const float c89 = p.actS[8] / s9v;
      const float4 b4 = *(const float4*)(p.bias + i);
      const float4 g4 = *(const float4*)(p.g2s9 + i);
      float c2[4];
      #pragma unroll
      for (int r = 0; r < 4; ++r) c2[r] = ((const float*)&b4)[r] / s3v;
      #pragma unroll
      for (int jj = 0; jj < 4; ++jj) {
        const int j = j0 + jj*16 + l15;
        const uint32_t pk8 = *(const uint32_t*)(p.X1qIn + (long)j*D_ + i);
        float4 o;
        #pragma unroll
        for (int r = 0; r < 4; ++r) {
          float q3 = rclipf(fmaf((float)acc[ii][jj][r], c1, c2[r]));
          float q8 = (float)(int8_t)(uint8_t)(pk8 >> (8*r));
          float q9 = rclipf(fmaf(q3, ((const float*)&g4)[r], q8 * c89));
          ((float*)&o)[r] = s9v * q9;
        }
        *(float4*)(p.outF + (long)j*D_ + i) = o;
      }
    }
  }
}

// ---------------- host launch ----------------
extern "C" void kernel_launch(void* const* d_in, const int* in_sizes, int n_in,
                              void* d_out, int out_size, void* d_ws, size_t ws_size,
                              hipStream_t stream) {
  (void)in_sizes; (void)n_in; (void)out_size; (void)ws_size;
  const float* x    = (const float*)d_in[0];
  const float* n1a  = (const float*)d_in[1];
  const float* n1b  = (const float*)d_in[2];
  const float* attw = (const float*)d_in[3];
  const float* attb = (const float*)d_in[4];
  const float* g1   = (const float*)d_in[5];
  const float* n2a  = (const float*)d_in[6];
  const float* n2b  = (const float*)d_in[7];
  const float* w1vt = (const float*)d_in[8];
  const float* b1vt = (const float*)d_in[9];
  const float* w1u  = (const float*)d_in[10];
  const float* b1u  = (const float*)d_in[11];
  const float* w2vt = (const float*)d_in[12];
  const float* b2vt = (const float*)d_in[13];
  const float* w2u  = (const float*)d_in[14];
  const float* b2u  = (const float*)d_in[15];
  const float* g2   = (const float*)d_in[16];
  const float* actS = (const float*)d_in[17];
  float* out = (float*)d_out;
  char* ws = (char*)d_ws;

  float*  amax = (float*)(ws + OFF_AMAX);
  int8_t* LUTG = (int8_t*)(ws + OFF_LUT);
  float*  qvec = (float*)(ws + OFF_QVEC);
  int8_t* WQA  = (int8_t*)(ws + OFF_WQA);
  int8_t* W1VT = (int8_t*)(ws + OFF_W1VT);
  int8_t* W1U  = (int8_t*)(ws + OFF_W1U);
  int8_t* W2VT = (int8_t*)(ws + OFF_W2VT);
  int8_t* W2U  = (int8_t*)(ws + OFF_W2U);
  int8_t* X1Q  = (int8_t*)(ws + OFF_X1Q);
  int8_t* A4   = (int8_t*)(ws + OFF_A4);
  int8_t* A7   = (int8_t*)(ws + OFF_A7);
  int8_t* A0T  = (int8_t*)(ws + OFF_A0T);
  int8_t* A2   = (int8_t*)(ws + OFF_A2);
  int8_t* A6   = (int8_t*)(ws + OFF_A6);

  hipMemsetAsync(amax, 0, 64, stream);
  absmax_k<<<dim3(32, 9), 256, 0, stream>>>(n1a, attw, g1, n2a, w1vt, w1u, w2vt, w2u, g2, amax);
  prep_vec_k<<<1, 768, 0, stream>>>(n1a, n1b, g1, n2a, n2b, g2, amax, actS, qvec, LUTG);
  quant_all_k<<<dim3(1152, 5), 256, 0, stream>>>(w1vt, w1u, w2vt, w2u, attw, amax,
                                                 W1VT, W1U, W2VT, W2U, WQA);
  stageA_k<<<dim3(12, 4, 128), 256, 0, stream>>>(x, qvec, qvec + 768, A0T);

  // attn (round-0 verified): per-batch Out[d,m] = sum_n A0T[b][d][n] * WQA[m][n]
  GemmParams pa = {};
  pa.A = A0T; pa.W = WQA; pa.K = 256; pa.MT = 6; pa.NT = 2;
  pa.batchStrideA = (long)D_*256;
  pa.actS = actS; pa.amax = amax; pa.amaxIdx = 1; pa.sInIdx = 0;
  pa.bias = attb; pa.xorg = x;
  pa.g1s = qvec + 1536; pa.a2s8 = qvec + 2304; pa.b2s = qvec + 3072;
  pa.X1q = X1Q; pa.A2 = A2;
  gemm_i8<0><<<dim3(12, 128), 256, 0, stream>>>(pa);

  // fc1_VT: A=W1VT [384][768], W=A2 [25088][768] -> A4  (BM=128, BN=256)
  GemmParams p1 = {};
  p1.A = W1VT; p1.W = A2; p1.K = D_; p1.MT = R_/128; p1.NT = TOK/256;
  p1.actS = actS; p1.amax = amax; p1.amaxIdx = 4; p1.sInIdx = 2; p1.sOutIdx = 4;
  p1.bias = b1vt; p1.out8 = A4; p1.ldOut = R_;
  gemm_ph<1, 4, 3, 768><<<dim3((R_/128)*(TOK/256)), 512, 0, stream>>>(p1);

  // fc1_U: A=W1U [3072][384], W=A4 -> GELU(LUT) -> A6  (BM=256, BN=256)
  GemmParams p2 = {};
  p2.A = W1U; p2.W = A4; p2.K = R_; p2.MT = H_/256; p2.NT = TOK/256;
  p2.actS = actS; p2.amax = amax; p2.amaxIdx = 5; p2.sInIdx = 4; p2.sOutIdx = 5;
  p2.bias = b1u; p2.out8 = A6; p2.ldOut = H_; p2.lutG = LUTG;
  gemm_ph<2, 8, 4, 384><<<dim3((H_/256)*(TOK/256)), 512, 0, stream>>>(p2);

  // fc2_VT: A=W2VT [384][3072], W=A6 -> A7  (BM=128, BN=256)
  GemmParams p3 = {};
  p3.A = W2VT; p3.W = A6; p3.K = H_; p3.MT = R_/128; p3.NT = TOK/256;
  p3.actS = actS; p3.amax = amax; p3.amaxIdx = 6; p3.sInIdx = 6; p3.sOutIdx = 7;
  p3.bias = b2vt; p3.out8 = A7; p3.ldOut = R_;
  gemm_ph<1, 4, 3, 3072><<<dim3((R_/128)*(TOK/256)), 512, 0, stream>>>(p3);

  // fc2_U: A=W2U [768][384], W=A7 -> gamma2 + residual -> out fp32  (BM=256, BN=256)
  GemmParams p4 = {};
  p4.A = W2U; p4.W = A7; p4.K = R_; p4.MT = D_/256; p4.NT = TOK/256;
  p4.actS = actS; p4.amax = amax; p4.amaxIdx = 7; p4.sInIdx = 7;
  p4.bias = b2u; p4.g2s9 = qvec + 3840; p4.X1qIn = X1Q; p4.outF = out; p4.ldOut = D_;
  gemm_ph<3, 8, 4, 384><<<dim3((D_/256)*(TOK/256)), 512, 0, stream>>>(p4);
}

// Round 3
// 518.308 us; speedup vs baseline: 1.0878x; 1.0793x over previous
//
#include <hip/hip_runtime.h>
#include <cstdint>
#include <cmath>

// Problem dims
#define B_   128
#define N_   196
#define D_   768
#define H_   3072
#define R_   384
#define TOK  (B_*N_)      // 25088

typedef int i32x4 __attribute__((ext_vector_type(4)));

// async global->LDS, 16B per lane; LDS dest = wave-uniform base + lane*16
#define GLDS16(g, l) __builtin_amdgcn_global_load_lds( \
    (const __attribute__((address_space(1))) void*)(g), \
    (__attribute__((address_space(3))) void*)(l), 16, 0, 0)

// s_waitcnt imm (gfx9): vmcnt[3:0], expcnt[6:4]=7, lgkmcnt[11:8]=15
#define WAITV4() __builtin_amdgcn_s_waitcnt(0xF74)   // vmcnt(4)
#define WAITV0() __builtin_amdgcn_s_waitcnt(0xF70)   // vmcnt(0)
#define WAITLGKM0() __asm__ volatile("s_waitcnt lgkmcnt(0)" ::: "memory")
#define BARRIER() do { __asm__ volatile("" ::: "memory"); \
                       __builtin_amdgcn_s_barrier(); \
                       __asm__ volatile("" ::: "memory"); } while (0)

// ---------------- workspace layout (bytes) ----------------
#define OFF_AMAX   0L
#define OFF_LUT    512L                  // 256-entry int8 GELU LUT
#define OFF_QVEC   1024L                 // 6 x 768 fp32 precomputed epilogue vectors
#define OFF_WQA    (32L*1024)            // attn weight int8 padded [256][256]
#define OFF_W1VT   (128L*1024)           // [384][768]
#define OFF_W1U    (512L*1024)           // [3072][384]
#define OFF_W2VT   (2L*1024*1024)        // [384][3072]
#define OFF_W2U    (3328L*1024)          // [768][384]
#define OFF_X1Q    (4L*1024*1024)        // int8 [25088][768]
#define OFF_A4     (24L*1024*1024)       // int8 [25088][384]
#define OFF_A7     (34L*1024*1024)       // int8 [25088][384]
#define OFF_A0T    (44L*1024*1024)       // int8 [128][768][256] (dead after attn)
#define OFF_A2     (68L*1024*1024)       // int8 [25088][768]    (dead after fc1_vt)
#define OFF_A6     (44L*1024*1024)       // int8 [25088][3072]   (overlays A0T+A2)

__device__ __forceinline__ float rclipf(float v) {
  // clip(round_half_even(v), -128, 127) ; matches jnp.clip(jnp.round(x),-n,n-1)
  return fminf(fmaxf(rintf(v), -128.f), 127.f);
}

// ---------------- absmax over 9 weight tensors ----------------
__global__ void absmax_k(const float* p0, const float* p1, const float* p2,
                         const float* p3, const float* p4, const float* p5,
                         const float* p6, const float* p7, const float* p8,
                         float* amax) {
  int tsel = blockIdx.y;
  const float* src; int n;
  switch (tsel) {
    case 0: src = p0; n = 768;     break;  // norm1_a
    case 1: src = p1; n = N_*N_;   break;  // attn_w
    case 2: src = p2; n = 768;     break;  // gamma1
    case 3: src = p3; n = 768;     break;  // norm2_a
    case 4: src = p4; n = R_*D_;   break;  // fc1_vt_w
    case 5: src = p5; n = H_*R_;   break;  // fc1_u_w
    case 6: src = p6; n = R_*H_;   break;  // fc2_vt_w
    case 7: src = p7; n = D_*R_;   break;  // fc2_u_w
    default: src = p8; n = 768;    break;  // gamma2
  }
  float m = 0.f;
  for (int i = blockIdx.x*blockDim.x + threadIdx.x; i < n; i += gridDim.x*blockDim.x)
    m = fmaxf(m, fabsf(src[i]));
  #pragma unroll
  for (int off = 32; off > 0; off >>= 1)
    m = fmaxf(m, __shfl_down(m, off));
  if ((threadIdx.x & 63) == 0)
    atomicMax((int*)(amax + tsel), __float_as_int(m));
}

// ---------------- precompute epilogue vectors + GELU LUT (1 block, 768 thr) ----------------
__global__ void prep_vec_k(const float* n1a, const float* n1b, const float* g1,
                           const float* n2a, const float* n2b, const float* g2,
                           const float* amax, const float* actS, float* dst,
                           int8_t* lut) {
  int i = threadIdx.x;  // 768
  float s0 = actS[0], s1 = actS[1], s2 = actS[2], s3 = actS[3];
  float s8 = actS[8], s9 = actS[9];
  float sw;
  sw = amax[0]/127.f + 1e-8f; float qn1a = sw * rclipf(n1a[i]/sw);
  dst[i]        = qn1a / s0;
  dst[768+i]    = n1b[i] / s0;
  sw = amax[2]/127.f + 1e-8f; float qg1 = sw * rclipf(g1[i]/sw);
  dst[1536+i]   = (s1 * qg1) / s8;
  sw = amax[3]/127.f + 1e-8f; float qn2a = sw * rclipf(n2a[i]/sw);
  dst[2304+i]   = (s8 * qn2a) / s2;
  dst[3072+i]   = n2b[i] / s2;
  sw = amax[8]/127.f + 1e-8f; float qg2 = sw * rclipf(g2[i]/sw);
  dst[3840+i]   = (s3 * qg2) / s9;
  if (i < 256) {
    float s5 = actS[5], s6 = actS[6];
    float v5 = s5 * (float)(i - 128);
    float g  = 0.5f * v5 * (1.f + erff(v5 * 0.70710678118654752f));
    lut[i] = (int8_t)(int)rclipf(g / s6);
  }
}

// ---------------- quantize all 5 matmul weights ----------------
__global__ void quant_all_k(const float* w1vt, const float* w1u, const float* w2vt,
                            const float* w2u, const float* attw, const float* amax,
                            int8_t* W1VT, int8_t* W1U, int8_t* W2VT, int8_t* W2U,
                            int8_t* WQA) {
  int sel = blockIdx.y;
  const float* src; int8_t* dst; int n; float am;
  switch (sel) {
    case 0: src = w1vt; dst = W1VT; n = R_*D_;  am = amax[4]; break;
    case 1: src = w1u;  dst = W1U;  n = H_*R_;  am = amax[5]; break;
    case 2: src = w2vt; dst = W2VT; n = R_*H_;  am = amax[6]; break;
    case 3: src = w2u;  dst = W2U;  n = D_*R_;  am = amax[7]; break;
    default: src = attw; dst = WQA; n = 65536;  am = amax[1]; break;
  }
  float s = am / 127.f + 1e-8f;
  if (sel < 4) {
    for (int i = blockIdx.x*blockDim.x + threadIdx.x; i < n; i += gridDim.x*blockDim.x)
      dst[i] = (int8_t)(int)rclipf(src[i] / s);
  } else {
    for (int i = blockIdx.x*blockDim.x + threadIdx.x; i < n; i += gridDim.x*blockDim.x) {
      int m = i >> 8, nn = i & 255;
      int8_t q = 0;
      if (m < N_ && nn < N_) q = (int8_t)(int)rclipf(attw[m*N_ + nn] / s);
      dst[i] = q;
    }
  }
}

// ---------------- stage A: norm1 affine + act-quant, transposed to A0T[b][d][n256] ----------------
__global__ void stageA_k(const float* __restrict__ x, const float* __restrict__ n1as,
                         const float* __restrict__ n1bs, int8_t* __restrict__ A0T) {
  __shared__ int8_t ldsT[64*68];
  const int dt = blockIdx.x;
  const int nt = blockIdx.y;
  const int b  = blockIdx.z;
  const int d0 = dt*64, n0 = nt*64;
  const int tid = threadIdx.x;
  const int dc = tid & 63, nr4 = tid >> 6;
  const float qa = n1as[d0 + dc];
  const float bb = n1bs[d0 + dc];
  #pragma unroll 4
  for (int it = 0; it < 16; ++it) {
    int nl = nr4 + it*4;
    int n = n0 + nl;
    int8_t q = 0;
    if (n < N_) {
      float v = fmaf(x[((long)b*N_ + n)*D_ + d0 + dc], qa, bb);
      q = (int8_t)(int)rclipf(v);
    }
    ldsT[dc*68 + nl] = q;
  }
  __syncthreads();
  const int k = tid & 15, dr = tid >> 4;
  #pragma unroll
  for (int it = 0; it < 4; ++it) {
    int d = dr + it*16;
    uint32_t v = *(const uint32_t*)(&ldsT[d*68 + k*4]);
    *(uint32_t*)(&A0T[(long)b*(D_*256) + (long)(d0+d)*256 + n0 + k*4]) = v;
  }
}

// ---------------- shared param struct ----------------
struct GemmParams {
  const int8_t* A;
  const int8_t* W;
  int K, MT, NT;
  long batchStrideA;
  const float* actS;
  const float* amax;
  int amaxIdx, sInIdx, sOutIdx, sOut2Idx;
  const float* bias;     // indexed by i (EPI 1/2/3) or j (EPI 0)
  int8_t* out8;
  int ldOut;
  const float* xorg;     // EPI0
  const float* g1s;
  const float* a2s8;
  const float* b2s;
  int8_t* X1q;
  int8_t* A2;
  const float* g2s9;     // EPI3
  const int8_t* X1qIn;
  float* outF;
  const int8_t* lutG;    // EPI2
};

// ---------------- attn GEMM (round-0 verified 128x128 2-phase, EPI0 only) ----------------
template<int EPI>
__launch_bounds__(256, 4)
__global__ void gemm_i8(GemmParams p) {
  __shared__ __align__(16) int8_t lsA[2][128][64];
  __shared__ __align__(16) int8_t lsB[2][128][64];
  const int K  = p.K;
  const int bx = blockIdx.x;
  const int mt = bx % p.MT;
  const int nt = bx / p.MT;
  const int t    = threadIdx.x;
  const int wid  = t >> 6;
  const int lane = t & 63;
  const int wm = wid & 1, wn = wid >> 1;
  const int quad = lane >> 4, l15 = lane & 15;

  const int8_t* Abase = p.A + (long)blockIdx.y * p.batchStrideA + (long)mt*128*K;
  const int8_t* Wbase = p.W + (long)nt*128*K;

  const int8_t* Ab = Abase + (long)(t >> 2)*K + (t & 3)*16;
  const int8_t* Bb = Wbase + (long)(t >> 2)*K + (t & 3)*16;
  const long half = 64L * K;

  auto issue = [&](int kt) {
    const int buf = kt & 1;
    const long k = (long)kt << 6;
    GLDS16(Ab + k,        &lsA[buf][0][0]  + t*16);
    GLDS16(Ab + half + k, &lsA[buf][64][0] + t*16);
    GLDS16(Bb + k,        &lsB[buf][0][0]  + t*16);
    GLDS16(Bb + half + k, &lsB[buf][64][0] + t*16);
  };

  const i32x4 zero = {0, 0, 0, 0};
  i32x4 acc[4][4];
  #pragma unroll
  for (int i = 0; i < 4; ++i)
    #pragma unroll
    for (int j = 0; j < 4; ++j) acc[i][j] = zero;

  const int KT = K >> 6;
  issue(0);
  for (int kt = 0; kt < KT; ++kt) {
    const int cur = kt & 1;
    if (kt + 1 < KT) { issue(kt + 1); WAITV4(); }
    else             { WAITV0(); }
    BARRIER();
    i32x4 af[4], bf[4];
    #pragma unroll
    for (int i = 0; i < 4; ++i)
      af[i] = *(const i32x4*)(&lsA[cur][wm*64 + i*16 + l15][quad*16]);
    #pragma unroll
    for (int j = 0; j < 4; ++j)
      bf[j] = *(const i32x4*)(&lsB[cur][wn*64 + j*16 + l15][quad*16]);
    #pragma unroll
    for (int i = 0; i < 4; ++i)
      #pragma unroll
      for (int j = 0; j < 4; ++j)
        acc[i][j] = __builtin_amdgcn_mfma_i32_16x16x64_i8(af[i], bf[j], acc[i][j], 0, 0, 0);
    BARRIER();
  }

  // ---- EPI0 epilogue: attn + gamma1 + residual + norm2 + act3 ----
  const float sW  = p.amax[p.amaxIdx] / 127.f + 1e-8f;
  const float sAB = p.actS[p.sInIdx] * sW;
  const int i0 = mt*128 + wm*64;
  const int j0 = nt*128 + wn*64;

  #pragma unroll
  for (int ii = 0; ii < 4; ++ii) {
    const int i = i0 + ii*16 + quad*4;   // d (0..767)
    const float c1     = sAB / p.actS[1];
    const float inv_s8 = 1.f / p.actS[8];
    const float4 g1s4 = *(const float4*)(p.g1s + i);
    const float4 a2s4 = *(const float4*)(p.a2s8 + i);
    const float4 b2s4 = *(const float4*)(p.b2s + i);
    #pragma unroll
    for (int jj = 0; jj < 4; ++jj) {
      const int j = j0 + jj*16 + l15;    // m patch
      if (j < N_) {
        const float c2 = p.bias[j] / p.actS[1];
        const long tok = (long)blockIdx.y * N_ + j;
        const float4 xo = *(const float4*)(p.xorg + tok*D_ + i);
        uint32_t pk8 = 0, pk2 = 0;
        #pragma unroll
        for (int r = 0; r < 4; ++r) {
          float accf = (float)acc[ii][jj][r];
          float q1 = rclipf(fmaf(accf, c1, c2));
          float q8 = rclipf(fmaf(q1, ((const float*)&g1s4)[r],
                                 ((const float*)&xo)[r] * inv_s8));
          float q2 = rclipf(fmaf(q8, ((const float*)&a2s4)[r],
                                 ((const float*)&b2s4)[r]));
          pk8 |= ((uint32_t)(uint8_t)(int8_t)(int)q8) << (8*r);
          pk2 |= ((uint32_t)(uint8_t)(int8_t)(int)q2) << (8*r);
        }
        *(uint32_t*)(p.X1q + tok*D_ + i) = pk8;
        *(uint32_t*)(p.A2  + tok*D_ + i) = pk2;
      }
    }
  }
}

// ---------------- 8-phase i8 GEMM (T2+T3+T4+T5): 512 thr, BMxBN = (MFR*32)x256 ----------------
// T2 both-sides swizzle: GLDS dest stays linear; global SOURCE col-group is
// pre-XOR'd with the LDS row's bits 1-2 ((t>>3)&3); ds_read applies the same
// XOR (quad ^ (l15>>1)&3). slot(row,q) = (row&1)*4 + (q^((row>>1)&3)) covers
// all 8 16B-slots/128B -> exactly 2 lanes/slot (free, m136).
// Epilogue: per-wave LDS bounce (reuses K-loop buffers after final barrier)
// -> dwordx4 coalesced global stores (128B contiguous per token row).
template<int EPI, int MFR, int NLD, int K>
__launch_bounds__(512, 2)
__global__ void gemm_ph(GemmParams p) {
  constexpr int BM = MFR * 32;        // 256 or 128
  constexpr int KT = K / 64;
  constexpr int HM = MFR / 2;
  constexpr int ASZ = 3*BM*64;
  constexpr int BSZ = 3*256*64;
  constexpr int SRB = BM/2 + 16;      // scratch row stride (bytes), mult of 16
  static_assert(8*64*SRB <= ASZ + BSZ, "epilogue scratch overflow");
  __shared__ __align__(16) int8_t lsMem[ASZ + BSZ];
  __shared__ uint32_t lutR[(EPI == 2) ? 64*32 : 4];  // bank-replicated GELU LUT

  const int t    = threadIdx.x;
  const int wid  = t >> 6;
  const int lane = t & 63;
  const int wm = wid & 1, wn = wid >> 1;              // waves 2 x 4
  const int quad = lane >> 4, l15 = lane & 15, l31 = lane & 31;

  if constexpr (EPI == 2) {
    if (t < 64) {
      const uint8_t* lg = (const uint8_t*)p.lutG + t*4;
      uint32_t v = (uint32_t)lg[0] | ((uint32_t)lg[1] << 8) |
                   ((uint32_t)lg[2] << 16) | ((uint32_t)lg[3] << 24);
      #pragma unroll
      for (int c = 0; c < 32; ++c) lutR[t*32 + c] = v;
    }
    __syncthreads();
  }

  // XCD-aware swizzle (T1) when grid divisible by 8
  int bx = blockIdx.x;
  { const int nwg = gridDim.x;
    if ((nwg & 7) == 0) { const int c = nwg >> 3; bx = (bx & 7)*c + (bx >> 3); } }
  const int mt = bx % p.MT;
  const int nt = bx / p.MT;

  // T2 staging-side pre-swizzle: thread t covers LDS row t>>2, col-group t&3;
  // its global source col-group = (t&3) ^ ((t>>3)&3)  (row bits 1-2)
  const int swz = ((t & 3) ^ ((t >> 3) & 3)) * 16;
  const int8_t* Ab = p.A + (long)mt*BM*K  + (long)(t >> 2)*K + swz;
  const int8_t* Bb = p.W + (long)nt*256*K + (long)(t >> 2)*K + swz;

  auto issue1 = [&](int buf, int kt, int ld) {
    const long kOff = (long)kt * 64;
    if constexpr (MFR == 8) {
      if (ld < 2) GLDS16(Ab + (long)ld*128*K + kOff,
                         lsMem + buf*(BM*64) + ld*8192 + t*16);
      else        GLDS16(Bb + (long)(ld-2)*128*K + kOff,
                         lsMem + ASZ + buf*(256*64) + (ld-2)*8192 + t*16);
    } else {
      if (ld == 0) GLDS16(Ab + kOff,
                          lsMem + buf*(BM*64) + t*16);
      else         GLDS16(Bb + (long)(ld-1)*128*K + kOff,
                          lsMem + ASZ + buf*(256*64) + (ld-1)*8192 + t*16);
    }
  };

  // T2 read-side XOR: same for A and B (row low bits come from l15)
  const int sq = (quad ^ ((l15 >> 1) & 3)) * 16;

  const i32x4 zero = {0, 0, 0, 0};
  i32x4 acc[MFR][4];
  #pragma unroll
  for (int i = 0; i < MFR; ++i)
    #pragma unroll
    for (int j = 0; j < 4; ++j) acc[i][j] = zero;

  // prologue: tiles 0 and 1 fully staged/in-flight
  #pragma unroll
  for (int ld = 0; ld < NLD; ++ld) issue1(0, 0, ld);
  #pragma unroll
  for (int ld = 0; ld < NLD; ++ld) issue1(1, 1, ld);
  __builtin_amdgcn_s_waitcnt(0xF70 | NLD);   // tile 0 landed, tile 1 in flight
  BARRIER();

  int bufR = 0, bufW = 2;
  #pragma unroll 1
  for (int kt = 0; kt < KT; ++kt) {
    const bool iss = (kt + 2 < KT);
    i32x4 af[MFR], bf[4];

    // ---- phase 0: af lower + bf[0:2]; MFMA quadrant (lo, left) ----
    #pragma unroll
    for (int i = 0; i < HM; ++i)
      af[i] = *(const i32x4*)(lsMem + (bufR*BM + wm*(BM/2) + i*16 + l15)*64 + sq);
    bf[0] = *(const i32x4*)(lsMem + ASZ + (bufR*256 + wn*64 +  0 + l15)*64 + sq);
    bf[1] = *(const i32x4*)(lsMem + ASZ + (bufR*256 + wn*64 + 16 + l15)*64 + sq);
    if (iss) issue1(bufW, kt + 2, 0);
    BARRIER();
    __builtin_amdgcn_s_setprio(1);
    #pragma unroll
    for (int i = 0; i < HM; ++i)
      #pragma unroll
      for (int j = 0; j < 2; ++j)
        acc[i][j] = __builtin_amdgcn_mfma_i32_16x16x64_i8(af[i], bf[j], acc[i][j], 0, 0, 0);
    __builtin_amdgcn_s_setprio(0);
    BARRIER();

    // ---- phase 1: af upper; MFMA quadrant (hi, left) ----
    #pragma unroll
    for (int i = HM; i < MFR; ++i)
      af[i] = *(const i32x4*)(lsMem + (bufR*BM + wm*(BM/2) + i*16 + l15)*64 + sq);
    if (iss && 1 < NLD) issue1(bufW, kt + 2, 1);
    BARRIER();
    __builtin_amdgcn_s_setprio(1);
    #pragma unroll
    for (int i = HM; i < MFR; ++i)
      #pragma unroll
      for (int j = 0; j < 2; ++j)
        acc[i][j] = __builtin_amdgcn_mfma_i32_16x16x64_i8(af[i], bf[j], acc[i][j], 0, 0, 0);
    __builtin_amdgcn_s_setprio(0);
    BARRIER();

    // ---- phase 2: bf[2:4]; MFMA quadrant (lo, right) ----
    bf[2] = *(const i32x4*)(lsMem + ASZ + (bufR*256 + wn*64 + 32 + l15)*64 + sq);
    bf[3] = *(const i32x4*)(lsMem + ASZ + (bufR*256 + wn*64 + 48 + l15)*64 + sq);
    if (iss && 2 < NLD) issue1(bufW, kt + 2, 2);
    BARRIER();
    __builtin_amdgcn_s_setprio(1);
    #pragma unroll
    for (int i = 0; i < HM; ++i)
      #pragma unroll
      for (int j = 2; j < 4; ++j)
        acc[i][j] = __builtin_amdgcn_mfma_i32_16x16x64_i8(af[i], bf[j], acc[i][j], 0, 0, 0);
    __builtin_amdgcn_s_setprio(0);
    BARRIER();

    // ---- phase 3: MFMA quadrant (hi, right); counted vmcnt for next tile ----
    if (iss && 3 < NLD) issue1(bufW, kt + 2, 3);
    BARRIER();
    __builtin_amdgcn_s_setprio(1);
    #pragma unroll
    for (int i = HM; i < MFR; ++i)
      #pragma unroll
      for (int j = 2; j < 4; ++j)
        acc[i][j] = __builtin_amdgcn_mfma_i32_16x16x64_i8(af[i], bf[j], acc[i][j], 0, 0, 0);
    __builtin_amdgcn_s_setprio(0);
    if (iss) __builtin_amdgcn_s_waitcnt(0xF70 | NLD);  // tile kt+1 landed; kt+2 in flight
    else     WAITV0();
    BARRIER();

    bufR = (bufR == 2) ? 0 : bufR + 1;
    bufW = (bufW == 2) ? 0 : bufW + 1;
  }
  // After this barrier all LDS reads are drained -> lsMem reusable as scratch.

  // ---- epilogue ---- C/D layout (16x16): col=lane&15 (j), row=quad*4+r (i)
  const float sW  = p.amax[p.amaxIdx] / 127.f + 1e-8f;
  const float sAB = p.actS[p.sInIdx] * sW;
  const int i0 = mt*BM + wm*(BM/2);
  const int j0 = nt*256 + wn*64;
  int8_t* scr = lsMem + wid * (64 * SRB);   // per-wave private scratch

  if constexpr (EPI == 1 || EPI == 2) {
    const float sO = p.actS[p.sOutIdx];
    const float c1 = sAB / sO;
    #pragma unroll
    for (int ii = 0; ii < MFR; ++ii) {
      const int i = i0 + ii*16 + quad*4;
      const float4 b4 = *(const float4*)(p.bias + i);
      float c2[4];
      #pragma unroll
      for (int r = 0; r < 4; ++r) c2[r] = ((const float*)&b4)[r] / sO;
      #pragma unroll
      for (int jj = 0; jj < 4; ++jj) {
        uint32_t pk = 0;
        #pragma unroll
        for (int r = 0; r < 4; ++r) {
          if constexpr (EPI == 1) {
            float q = rclipf(fmaf((float)acc[ii][jj][r], c1, c2[r]));
            pk |= ((uint32_t)(uint8_t)(int8_t)(int)q) << (8*r);
          } else {
            int q5 = (int)rclipf(fmaf((float)acc[ii][jj][r], c1, c2[r])) + 128;
            uint32_t v = lutR[(q5 >> 2)*32 + l31];
            pk |= ((v >> ((q5 & 3)*8)) & 0xffu) << (8*r);
          }
        }
        const int row = jj*16 + l15;
        *(uint32_t*)(scr + row*SRB + ii*16 + quad*4) = pk;
      }
    }
    WAITLGKM0();
    constexpr int CH = (BM/2)/16;          // dwordx4 chunks per token row
    #pragma unroll
    for (int e = 0; e < CH; ++e) {         // 64*CH chunks / 64 lanes
      const int c = e*64 + lane;
      const int row = c / CH, cc = c % CH;
      i32x4 v = *(const i32x4*)(scr + row*SRB + cc*16);
      *(i32x4*)(p.out8 + (long)(j0 + row)*p.ldOut + i0 + cc*16) = v;
    }
  } else {  // EPI == 3: block act4 + gamma2 + residual(X1q) + add_2 -> fp32
    const float s3v = p.actS[3], s9v = p.actS[9];
    const float c1  = sAB / s3v;
    const float c89 = p.actS[8] / s9v;
    #pragma unroll
    for (int pp = 0; pp < 4; ++pp) {       // 32-feature passes (8KB scratch each)
      #pragma unroll
      for (int iu = 0; iu < 2; ++iu) {
        const int ii = pp*2 + iu;
        const int i = i0 + ii*16 + quad*4;
        const float4 b4 = *(const float4*)(p.bias + i);
        const float4 g4 = *(const float4*)(p.g2s9 + i);
        float c2[4];
        #pragma unroll
        for (int r = 0; r < 4; ++r) c2[r] = ((const float*)&b4)[r] / s3v;
        #pragma unroll
        for (int jj = 0; jj < 4; ++jj) {
          const int j = j0 + jj*16 + l15;
          const uint32_t pk8 = *(const uint32_t*)(p.X1qIn + (long)j*D_ + i);
          float4 o;
          #pragma unroll
          for (int r = 0; r < 4; ++r) {
            float q3 = rclipf(fmaf((float)acc[ii][jj][r], c1, c2[r]));
            float q8 = (float)(int8_t)(uint8_t)(pk8 >> (8*r));
            float q9 = rclipf(fmaf(q3, ((const float*)&g4)[r], q8 * c89));
            ((float*)&o)[r] = s9v * q9;
          }
          const int row = jj*16 + l15;
          *(float4*)(scr + row*SRB + iu*64 + quad*16) = o;
        }
      }
      WAITLGKM0();
      #pragma unroll
      for (int e = 0; e < 8; ++e) {        // 512 float4 chunks / 64 lanes
        const int c = e*64 + lane;
        const int row = c >> 3, cc = c & 7;
        float4 v = *(const float4*)(scr + row*SRB + cc*16);
        *(float4*)(p.outF + (long)(j0 + row)*D_ + i0 + pp*32 + cc*4) = v;
      }
      WAITLGKM0();                         // reads done before next pass overwrites
    }
  }
}

// ---------------- host launch ----------------
extern "C" void kernel_launch(void* const* d_in, const int* in_sizes, int n_in,
                              void* d_out, int out_size, void* d_ws, size_t ws_size,
                              hipStream_t stream) {
  (void)in_sizes; (void)n_in; (void)out_size; (void)ws_size;
  const float* x    = (const float*)d_in[0];
  const float* n1a  = (const float*)d_in[1];
  const float* n1b  = (const float*)d_in[2];
  const float* attw = (const float*)d_in[3];
  const float* attb = (const float*)d_in[4];
  const float* g1   = (const float*)d_in[5];
  const float* n2a  = (const float*)d_in[6];
  const float* n2b  = (const float*)d_in[7];
  const float* w1vt = (const float*)d_in[8];
  const float* b1vt = (const float*)d_in[9];
  const float* w1u  = (const float*)d_in[10];
  const float* b1u  = (const float*)d_in[11];
  const float* w2vt = (const float*)d_in[12];
  const float* b2vt = (const float*)d_in[13];
  const float* w2u  = (const float*)d_in[14];
  const float* b2u  = (const float*)d_in[15];
  const float* g2   = (const float*)d_in[16];
  const float* actS = (const float*)d_in[17];
  float* out = (float*)d_out;
  char* ws = (char*)d_ws;

  float*  amax = (float*)(ws + OFF_AMAX);
  int8_t* LUTG = (int8_t*)(ws + OFF_LUT);
  float*  qvec = (float*)(ws + OFF_QVEC);
  int8_t* WQA  = (int8_t*)(ws + OFF_WQA);
  int8_t* W1VT = (int8_t*)(ws + OFF_W1VT);
  int8_t* W1U  = (int8_t*)(ws + OFF_W1U);
  int8_t* W2VT = (int8_t*)(ws + OFF_W2VT);
  int8_t* W2U  = (int8_t*)(ws + OFF_W2U);
  int8_t* X1Q  = (int8_t*)(ws + OFF_X1Q);
  int8_t* A4   = (int8_t*)(ws + OFF_A4);
  int8_t* A7   = (int8_t*)(ws + OFF_A7);
  int8_t* A0T  = (int8_t*)(ws + OFF_A0T);
  int8_t* A2   = (int8_t*)(ws + OFF_A2);
  int8_t* A6   = (int8_t*)(ws + OFF_A6);

  hipMemsetAsync(amax, 0, 64, stream);
  absmax_k<<<dim3(32, 9), 256, 0, stream>>>(n1a, attw, g1, n2a, w1vt, w1u, w2vt, w2u, g2, amax);
  prep_vec_k<<<1, 768, 0, stream>>>(n1a, n1b, g1, n2a, n2b, g2, amax, actS, qvec, LUTG);
  quant_all_k<<<dim3(1152, 5), 256, 0, stream>>>(w1vt, w1u, w2vt, w2u, attw, amax,
                                                 W1VT, W1U, W2VT, W2U, WQA);
  stageA_k<<<dim3(12, 4, 128), 256, 0, stream>>>(x, qvec, qvec + 768, A0T);

  // attn (round-0 verified): per-batch Out[d,m] = sum_n A0T[b][d][n] * WQA[m][n]
  GemmParams pa = {};
  pa.A = A0T; pa.W = WQA; pa.K = 256; pa.MT = 6; pa.NT = 2;
  pa.batchStrideA = (long)D_*256;
  pa.actS = actS; pa.amax = amax; pa.amaxIdx = 1; pa.sInIdx = 0;
  pa.bias = attb; pa.xorg = x;
  pa.g1s = qvec + 1536; pa.a2s8 = qvec + 2304; pa.b2s = qvec + 3072;
  pa.X1q = X1Q; pa.A2 = A2;
  gemm_i8<0><<<dim3(12, 128), 256, 0, stream>>>(pa);

  // fc1_VT: A=W1VT [384][768], W=A2 [25088][768] -> A4  (BM=128, BN=256)
  GemmParams p1 = {};
  p1.A = W1VT; p1.W = A2; p1.K = D_; p1.MT = R_/128; p1.NT = TOK/256;
  p1.actS = actS; p1.amax = amax; p1.amaxIdx = 4; p1.sInIdx = 2; p1.sOutIdx = 4;
  p1.bias = b1vt; p1.out8 = A4; p1.ldOut = R_;
  gemm_ph<1, 4, 3, 768><<<dim3((R_/128)*(TOK/256)), 512, 0, stream>>>(p1);

  // fc1_U: A=W1U [3072][384], W=A4 -> GELU(LUT) -> A6  (BM=256, BN=256)
  GemmParams p2 = {};
  p2.A = W1U; p2.W = A4; p2.K = R_; p2.MT = H_/256; p2.NT = TOK/256;
  p2.actS = actS; p2.amax = amax; p2.amaxIdx = 5; p2.sInIdx = 4; p2.sOutIdx = 5;
  p2.bias = b1u; p2.out8 = A6; p2.ldOut = H_; p2.lutG = LUTG;
  gemm_ph<2, 8, 4, 384><<<dim3((H_/256)*(TOK/256)), 512, 0, stream>>>(p2);

  // fc2_VT: A=W2VT [384][3072], W=A6 -> A7  (BM=128, BN=256)
  GemmParams p3 = {};
  p3.A = W2VT; p3.W = A6; p3.K = H_; p3.MT = R_/128; p3.NT = TOK/256;
  p3.actS = actS; p3.amax = amax; p3.amaxIdx = 6; p3.sInIdx = 6; p3.sOutIdx = 7;
  p3.bias = b2vt; p3.out8 = A7; p3.ldOut = R_;
  gemm_ph<1, 4, 3, 3072><<<dim3((R_/128)*(TOK/256)), 512, 0, stream>>>(p3);

  // fc2_U: A=W2U [768][384], W=A7 -> gamma2 + residual -> out fp32  (BM=256, BN=256)
  GemmParams p4 = {};
  p4.A = W2U; p4.W = A7; p4.K = R_; p4.MT = D_/256; p4.NT = TOK/256;
  p4.actS = actS; p4.amax = amax; p4.amaxIdx = 7; p4.sInIdx = 7;
  p4.bias = b2u; p4.g2s9 = qvec + 3840; p4.X1qIn = X1Q; p4.outF = out; p4.ldOut = D_;
  gemm_ph<3, 8, 4, 384><<<dim3((D_/256)*(TOK/256)), 512, 0, stream>>>(p4);
}